// Round 12
// baseline (489.733 us; speedup 1.0000x reference)
//
#include <hip/hip_runtime.h>
#include <stdint.h>

typedef float  f32x4  __attribute__((ext_vector_type(4)));
typedef short  short8 __attribute__((ext_vector_type(8)));
typedef __bf16 bf16x8 __attribute__((ext_vector_type(8)));

__device__ __forceinline__ unsigned short f2bf(float f) {
    unsigned u = __builtin_bit_cast(unsigned, f);
    unsigned r = u + 0x7fffu + ((u >> 16) & 1u);   // round-to-nearest-even
    return (unsigned short)(r >> 16);
}

__device__ __forceinline__ short8 cvt8(f32x4 a, f32x4 b) {
    short8 r;
    r[0] = (short)f2bf(a[0]); r[1] = (short)f2bf(a[1]);
    r[2] = (short)f2bf(a[2]); r[3] = (short)f2bf(a[3]);
    r[4] = (short)f2bf(b[0]); r[5] = (short)f2bf(b[1]);
    r[6] = (short)f2bf(b[2]); r[7] = (short)f2bf(b[3]);
    return r;
}

typedef const __attribute__((address_space(1))) void* gas_p;
typedef __attribute__((address_space(3))) void*       las_p;
__device__ __forceinline__ void gld_lds16(const void* g, void* l) {
    __builtin_amdgcn_global_load_lds((gas_p)g, (las_p)l, 16, 0, 0);
}

__device__ __forceinline__ f32x4 mfma16(short8 a, short8 b, f32x4 c) {
    return __builtin_amdgcn_mfma_f32_16x16x32_bf16(
        __builtin_bit_cast(bf16x8, a), __builtin_bit_cast(bf16x8, b), c, 0, 0, 0);
}

// ---------------------------------------------------------------------------
// Small GEMM:  St[n][m] = sum_k X[m][k] * W[k][n]   (K = 128 fixed)
// (unchanged — validated, ~2% of runtime)
// ---------------------------------------------------------------------------
template<int NMAT>
__global__ __launch_bounds__(256) void k_xw_t(const float* __restrict__ X,
                                              const float* __restrict__ W,
                                              short* __restrict__ St, int M) {
    constexpr int K   = 128;
    constexpr int NPT = NMAT / 4;
    __shared__ float Xs[64][129];
    __shared__ float Ws[K][NMAT];

    const int tid = threadIdx.x;
    const int m0  = blockIdx.x * 64;

    constexpr int WCH = K * NMAT / 4 / 256;
    #pragma unroll
    for (int j = 0; j < WCH; ++j) {
        int ch = tid + j * 256;
        ((float4*)Ws)[ch] = ((const float4*)W)[ch];
    }
    #pragma unroll
    for (int j = 0; j < 8; ++j) {
        int ch = tid + j * 256;
        int r = ch >> 5, c4 = ch & 31;
        float4 v = *(const float4*)(X + (size_t)(m0 + r) * K + c4 * 4);
        Xs[r][c4 * 4 + 0] = v.x; Xs[r][c4 * 4 + 1] = v.y;
        Xs[r][c4 * 4 + 2] = v.z; Xs[r][c4 * 4 + 3] = v.w;
    }
    __syncthreads();

    const int m  = tid & 63;
    const int n0 = (tid >> 6) * NPT;
    float acc[NPT];
    #pragma unroll
    for (int i = 0; i < NPT; ++i) acc[i] = 0.f;

    for (int k = 0; k < K; ++k) {
        float x = Xs[m][k];
        #pragma unroll
        for (int i = 0; i < NPT; i += 4) {
            float4 w = *(const float4*)&Ws[k][n0 + i];
            acc[i + 0] += x * w.x; acc[i + 1] += x * w.y;
            acc[i + 2] += x * w.z; acc[i + 3] += x * w.w;
        }
    }
    #pragma unroll
    for (int i = 0; i < NPT; ++i)
        St[(size_t)(n0 + i) * M + m0 + m] = (short)f2bf(acc[i]);
}

// ---------------------------------------------------------------------------
// Streaming GEMM:  out[m][n] = sum_k adj[m][k] * S[k][n]  (+bias, opt. relu)
//  v12 = v11 + BURST-PHASE schedule (r11 post-mortem: the per-iter B forcing
//  dragged each A batch to retirement within 2 iters of issue -> A in flight
//  only ~60% of the time). Now a cycle = 4 iters; at p0 ONLY we stage the
//  next cycle's B burst (4 tiles -> 4 of 8 LDS bufs) AND A batch (4 tiles ->
//  ping-pong reg array), both one full cycle ahead. p1-p3 stage nothing.
//  => A batches in flight back-to-back (iters [4c,4c+4)): ~100% duty.
//  - Per-phase waits vmcnt(7BCH+32 / 6BCH+32 / 5BCH+32 / 4BCH+32) force
//    exactly B(t), keep the whole current burst in flight. (<=63 legal.)
//  - 8 B-buffers: staged buf last read 7 iters/barriers earlier (WAR safe).
//    ONE barrier per iter. Wave-exclusive A rows (zero duplication).
//  - XOR swizzle (row&7)<<4 on B (pre-swizzled DMA source, linear dest).
//  - Tail cycle stages wrapped dummy tiles (count-uniform, never consumed).
//  Accumulation order identical to v9/v11 -> absmax unchanged.
// ---------------------------------------------------------------------------
template<int BN, bool RELU>
__global__ __launch_bounds__(256, 1) void k_adj_gemm(const float* __restrict__ A,
                                                     const short* __restrict__ Bt,
                                                     const float* __restrict__ bias,
                                                     float* __restrict__ out,
                                                     int M, int K) {
    constexpr int BM   = 64, BK = 64;
    constexpr int NF   = BN / 16;                    // n-frags (full width): 8 or 4
    constexpr int BCH  = BN * BK * 2 / (256 * 16);   // B-DMA per thread per tile: 4 or 2
    constexpr int VM0  = 7 * BCH + 32;               // p0: force B(4c)   (60 / 46)
    constexpr int VM1  = 6 * BCH + 32;               // p1: force B(4c+1) (56 / 44)
    constexpr int VM2  = 5 * BCH + 32;               // p2                (52 / 42)
    constexpr int VM3  = 4 * BCH + 32;               // p3                (48 / 40)

    __shared__ short Bs[8][BN * 64];                 // 8 x 16/8 KB

    const int tid  = threadIdx.x;
    const int wave = tid >> 6, lane = tid & 63;
    const int lr   = lane & 15, lk = lane >> 4;
    const int row0 = blockIdx.x * BM;
    const int row_g = row0 + wave * 16 + lr;         // wave-exclusive rows

    const char* Abase = (const char*)A + (size_t)row_g * K * 4 + lk * 32;

    const int key   = (lr & 7) << 4;                 // XOR swizzle key
    const int offs0 = (lk * 16) ^ key;               // B k-half 0
    const int offs1 = (64 + lk * 16) ^ key;          // B k-half 1

    f32x4 acc[NF];
    #pragma unroll
    for (int n = 0; n < NF; ++n) acc[n] = (f32x4)0.f;

    f32x4 bA0[16], bA1[16];                          // ping-pong 4-tile batches
    const int NT  = K / BK;                          // 256
    const int NTM = NT - 1;

#define LOAD_SLOT(QARR, BI, TT)                                                 \
    {                                                                           \
        const char* p = Abase + (size_t)(TT) * 256;                             \
        QARR[(BI) + 0] = *(const f32x4*)(p);                                    \
        QARR[(BI) + 1] = *(const f32x4*)(p + 16);                               \
        QARR[(BI) + 2] = *(const f32x4*)(p + 128);                              \
        QARR[(BI) + 3] = *(const f32x4*)(p + 144);                              \
    }
#define LOAD_BATCH(QARR, T0)                                                    \
    {                                                                           \
        LOAD_SLOT(QARR, 0,  ((T0) + 0) & NTM)                                   \
        LOAD_SLOT(QARR, 4,  ((T0) + 1) & NTM)                                   \
        LOAD_SLOT(QARR, 8,  ((T0) + 2) & NTM)                                   \
        LOAD_SLOT(QARR, 12, ((T0) + 3) & NTM)                                   \
    }
#define STAGE_B1(BUF, KTP)                                                      \
    {                                                                           \
        _Pragma("unroll")                                                       \
        for (int j = 0; j < BCH; ++j) {                                         \
            int o = (tid + j * 256) * 16;        /* linear byte off, B tile */  \
            int r = o >> 7, w = o & 127;                                        \
            const char* src = (const char*)Bt + (size_t)r * (K * 2)             \
                              + (size_t)((KTP) & NTM) * 128 + (w ^ ((r & 7) << 4)); \
            gld_lds16(src, (char*)&Bs[BUF][0] + o);                             \
        }                                                                       \
    }
// burst: B tiles T0..T0+3 into bufs BF0..BF0+3, then A batch T0..T0+3
#define STAGE_BURST(BF0, QARR, T0)                                              \
    STAGE_B1((BF0) + 0, (T0) + 0)                                               \
    STAGE_B1((BF0) + 1, (T0) + 1)                                               \
    STAGE_B1((BF0) + 2, (T0) + 2)                                               \
    STAGE_B1((BF0) + 3, (T0) + 3)                                               \
    LOAD_BATCH(QARR, T0)

    // prologue = burst "-1": B(0..3) -> bufs 0..3, A(0..3) -> bA1
    STAGE_BURST(0, bA1, 0)

#define ITER(KT, QARR, J4, CB, VM, STAGE_STMT)                                  \
    {                                                                           \
        /* cvt A(t) (compiler wait lands exactly on these 4 slots) */           \
        short8 fa0 = cvt8(QARR[(J4) + 0], QARR[(J4) + 1]);                      \
        short8 fa1 = cvt8(QARR[(J4) + 2], QARR[(J4) + 3]);                      \
        STAGE_STMT                                                              \
        __builtin_amdgcn_sched_barrier(0);                                      \
        /* force B(t) retired; current burst stays fully in flight */           \
        asm volatile("s_waitcnt vmcnt(%0)" :: "i"(VM) : "memory");              \
        __builtin_amdgcn_s_barrier();            /* the ONLY barrier */         \
        __builtin_amdgcn_sched_barrier(0);                                      \
        _Pragma("unroll")                                                       \
        for (int n = 0; n < NF; ++n) {                                          \
            short8 b0 = *(const short8*)((const char*)&Bs[CB][0]                \
                                         + n * 2048 + lr * 128 + offs0);        \
            acc[n] = mfma16(fa0, b0, acc[n]);                                   \
            short8 b1 = *(const short8*)((const char*)&Bs[CB][0]                \
                                         + n * 2048 + lr * 128 + offs1);        \
            acc[n] = mfma16(fa1, b1, acc[n]);                                   \
        }                                                                       \
    }

    // 64 cycles of 4 iters; unroll 2 cycles for static buffer indices.
    // even cycle: consume bA1 + bufs 0..3, stage bA0 + bufs 4..7 (tiles t+4..7)
    // odd  cycle: consume bA0 + bufs 4..7, stage bA1 + bufs 0..3
    for (int d = 0; d < 32; ++d) {
        int t = d * 8;
        ITER(t + 0, bA1, 0,  0, VM0, STAGE_BURST(4, bA0, (t) + 4))
        ITER(t + 1, bA1, 4,  1, VM1, )
        ITER(t + 2, bA1, 8,  2, VM2, )
        ITER(t + 3, bA1, 12, 3, VM3, )
        ITER(t + 4, bA0, 0,  4, VM0, STAGE_BURST(0, bA1, (t) + 8))
        ITER(t + 5, bA0, 4,  5, VM1, )
        ITER(t + 6, bA0, 8,  6, VM2, )
        ITER(t + 7, bA0, 12, 7, VM3, )
    }
#undef ITER
#undef STAGE_BURST
#undef STAGE_B1
#undef LOAD_BATCH
#undef LOAD_SLOT

    // epilogue: D layout col = lane&15, row = (lane>>4)*4 + j  [m89-verified]
    #pragma unroll
    for (int n = 0; n < NF; ++n) {
        int col = n * 16 + lr;
        float bv = bias[col];
        #pragma unroll
        for (int j = 0; j < 4; ++j) {
            int row = row0 + wave * 16 + lk * 4 + j;
            float v = acc[n][j] + bv;
            if (RELU) v = fmaxf(v, 0.f);
            out[(size_t)row * BN + col] = v;
        }
    }
}

extern "C" void kernel_launch(void* const* d_in, const int* in_sizes, int n_in,
                              void* d_out, int out_size, void* d_ws, size_t ws_size,
                              hipStream_t stream) {
    const int N = 16384, NH1 = 128, NH2 = 64;
    const float* feature = (const float*)d_in[0];
    const float* adj     = (const float*)d_in[1];
    const float* W1      = (const float*)d_in[2];
    const float* b1      = (const float*)d_in[3];
    const float* W2      = (const float*)d_in[4];
    const float* b2      = (const float*)d_in[5];

    short* S1t = (short*)d_ws;                            // [128][16384] bf16, 4 MiB
    float* h   = (float*)((char*)d_ws + (4u << 20));      // [16384][128] fp32, 8 MiB
    short* S2t = (short*)((char*)d_ws + (12u << 20));     // [64][16384]  bf16, 2 MiB

    k_xw_t<NH1><<<N / 64, 256, 0, stream>>>(feature, W1, S1t, N);
    k_adj_gemm<NH1, true ><<<N / 64, 256, 0, stream>>>(adj, S1t, b1, h, N, N);
    k_xw_t<NH2><<<N / 64, 256, 0, stream>>>(h, W2, S2t, N);
    k_adj_gemm<NH2, false><<<N / 64, 256, 0, stream>>>(adj, S2t, b2, (float*)d_out, N, N);
    (void)in_sizes; (void)n_in; (void)out_size; (void)ws_size;
}